// Round 10
// baseline (165.817 us; speedup 1.0000x reference)
//
#include <hip/hip_runtime.h>

// WaveConv3d, reduced form:
//   s_k  = signed 4x4x4 block-reduce of x  (8 subbands, 16^3 per (b,c))
//   ih   = sparse 3D DFT of s_k (6x6x3 freqs)
//   oh   = per-frequency 64->64 channel mix
//   out  = x - mean_{2x2x2}(x) + (1/8) sum_k sign_k(cell) * idft(oh_k)
// K1 = analyze + z/y-DFT -> g2 (DFT stages spread over all 256 lanes).
// K2 = in-LDS x-DFT + mix reading w directly (NT, read-once).
// K3 = inverse DFT + synthesis; LDS stage-aliased to 24.3 KB (6 blocks/CU),
// paired load/store streaming, NT out stores, reversed bo for LLC locality.

typedef float f32x4 __attribute__((ext_vector_type(4)));

__constant__ float C16c[16] = {
  1.0f, 0.92387953251128675f, 0.70710678118654752f, 0.38268343236508977f,
  0.0f, -0.38268343236508977f, -0.70710678118654752f, -0.92387953251128675f,
  -1.0f, -0.92387953251128675f, -0.70710678118654752f, -0.38268343236508977f,
  0.0f, 0.38268343236508977f, 0.70710678118654752f, 0.92387953251128675f
};
__constant__ float S16c[16] = {
  0.0f, 0.38268343236508977f, 0.70710678118654752f, 0.92387953251128675f,
  1.0f, 0.92387953251128675f, 0.70710678118654752f, 0.38268343236508977f,
  0.0f, -0.38268343236508977f, -0.70710678118654752f, -0.92387953251128675f,
  -1.0f, -0.92387953251128675f, -0.70710678118654752f, -0.38268343236508977f
};
__constant__ int KYv[6] = {0, 1, 2, 13, 14, 15};

// ---------------------------------------------------------------------------
// K1: fused analyze + z-DFT + y-DFT. WG = (bc, px).
// g2 layout: [b][row 144][px 16][c 64], row = k*18 + kyi*3 + kz.
__global__ __launch_bounds__(256) void k1_front(const float* __restrict__ x,
                                                float2* __restrict__ g2) {
  __shared__ float sm[8 * 272 + 8];   // [k][py][pz(17)]
  __shared__ float2 fz[8 * 51];       // [k][kz][ny(17)]
  __shared__ float2 ps[288];          // y-DFT half-sums
  unsigned tid = threadIdx.x;
  unsigned px = blockIdx.x & 15u;
  unsigned bc = blockIdx.x >> 4;
  unsigned c = bc & 63u, b = bc >> 6;
  const f32x4* xp4 = (const f32x4*)(x + ((size_t)bc << 18)) + (size_t)px * 4096u;
  unsigned z4 = tid & 15u;
#pragma unroll
  for (int q = 0; q < 4; q++) {
    float a00 = 0.f, a01 = 0.f, a10 = 0.f, a11 = 0.f;  // [dx][zhalf]
#pragma unroll
    for (int i = 0; i < 4; i++) {
      f32x4 v = xp4[i * 1024 + q * 256 + tid];
      float h0 = v.x + v.y, h1 = v.z + v.w;
      a00 += h0; a01 += h1;
      if (i < 2) { a10 += h0; a11 += h1; } else { a10 -= h0; a11 -= h1; }
    }
    float p00 = a00 + __shfl_xor(a00, 16);
    float p01 = a01 + __shfl_xor(a01, 16);
    float p10 = a10 + __shfl_xor(a10, 16);
    float p11 = a11 + __shfl_xor(a11, 16);
    float q00 = __shfl_xor(p00, 32), q01 = __shfl_xor(p01, 32);
    float q10 = __shfl_xor(p10, 32), q11 = __shfl_xor(p11, 32);
    bool hi = (tid >> 5) & 1u;
    float ya0 = p00 + q00, yd0 = hi ? (q00 - p00) : (p00 - q00);
    float ya1 = p01 + q01, yd1 = hi ? (q01 - p01) : (p01 - q01);
    float za0 = p10 + q10, zd0 = hi ? (q10 - p10) : (p10 - q10);
    float za1 = p11 + q11, zd1 = hi ? (q11 - p11) : (p11 - q11);
    if (((tid >> 4) & 3u) == 0u) {
      unsigned py = q * 4 + (tid >> 6);
      float* smp = sm + py * 17u + z4;
      smp[0 * 272] = (ya0 + ya1) * 0.125f;   // k=000
      smp[1 * 272] = (ya0 - ya1) * 0.125f;   // 001
      smp[2 * 272] = (yd0 + yd1) * 0.125f;   // 010
      smp[3 * 272] = (yd0 - yd1) * 0.125f;   // 011
      smp[4 * 272] = (za0 + za1) * 0.125f;   // 100
      smp[5 * 272] = (za0 - za1) * 0.125f;   // 101
      smp[6 * 272] = (zd0 + zd1) * 0.125f;   // 110
      smp[7 * 272] = (zd0 - zd1) * 0.125f;   // 111
    }
  }
  __syncthreads();
  // z-DFT: 384 items (k,y,kz) spread over all 256 lanes
  for (unsigned it = tid; it < 384u; it += 256u) {
    unsigned k = it / 48u, rem = it - k * 48u;
    unsigned y = rem / 3u, kz = rem - y * 3u;
    const float* row = sm + k * 272u + y * 17u;
    float re = 0.f, im = 0.f;
#pragma unroll
    for (int nz = 0; nz < 16; nz++) {
      float vv = row[nz];
      int t16 = (kz * nz) & 15;
      re += vv * C16c[t16];
      im -= vv * S16c[t16];
    }
    fz[k * 51u + kz * 17u + y] = make_float2(re, im);
  }
  __syncthreads();
  // y-DFT half-sums: 288 items = (row 144, half 2)
  for (unsigned it = tid; it < 288u; it += 256u) {
    unsigned r144 = it >> 1, h = it & 1u;
    unsigned k = r144 / 18u, r = r144 - k * 18u;
    unsigned kyi = r / 3u, kz = r - kyi * 3u;
    int ky = KYv[kyi];
    float re = 0.f, im = 0.f;
    unsigned ny0 = h * 8u;
#pragma unroll
    for (unsigned j = 0; j < 8u; j++) {
      unsigned ny = ny0 + j;
      float2 vv = fz[k * 51u + kz * 17u + ny];
      int t16 = ((unsigned)ky * ny) & 15;
      float cc = C16c[t16], sn = S16c[t16];
      re += vv.x * cc + vv.y * sn;
      im += vv.y * cc - vv.x * sn;
    }
    ps[it] = make_float2(re, im);
  }
  __syncthreads();
  if (tid < 144u) {
    float2 a = ps[2u * tid], bb = ps[2u * tid + 1u];
    g2[(((size_t)b * 144u + tid) * 16u + px) * 64u + c] =
        make_float2(a.x + bb.x, a.y + bb.y);
  }
}

// ---------------------------------------------------------------------------
// K2: x-DFT (in-LDS, per-corner) + channel mix reading w directly.
__global__ __launch_bounds__(256) void k2_mix(const float* __restrict__ w2,
                                              const float2* __restrict__ g2,
                                              float2* __restrict__ oh2) {
  __shared__ float2 ihl[4][64][27];   // [b][i=c][f]  55296 B
  unsigned tid = threadIdx.x;
  unsigned kc = blockIdx.x >> 3;
  unsigned ob = blockIdx.x & 7u;
  unsigned k = kc >> 2, corner = kc & 3u;
  unsigned kxi0 = 3u * (corner & 1u), kyi0 = 3u * (corner >> 1);
  {  // prologue: thread = (b, c)
    unsigned c = tid & 63u, b = tid >> 6;
    const float2* gb = g2 + ((size_t)b * 144u * 16u) * 64u + c;
#pragma unroll
    for (unsigned kyl = 0; kyl < 3u; kyl++) {
#pragma unroll
      for (unsigned kz = 0; kz < 3u; kz++) {
        unsigned row = k * 18u + (kyl + kyi0) * 3u + kz;
        float2 rg[16];
#pragma unroll
        for (int nx = 0; nx < 16; nx++) rg[nx] = gb[((size_t)row * 16u + nx) * 64u];
#pragma unroll
        for (unsigned kxl = 0; kxl < 3u; kxl++) {
          int kx = KYv[kxl + kxi0];
          float re = 0.f, im = 0.f;
#pragma unroll
          for (int nx = 0; nx < 16; nx++) {
            int t16 = (kx * nx) & 15;
            float cc = C16c[t16], sn = S16c[t16];
            re += rg[nx].x * cc + rg[nx].y * sn;
            im += rg[nx].y * cc - rg[nx].x * sn;
          }
          ihl[b][c][kxl * 9u + kyl * 3u + kz] = make_float2(re, im);
        }
      }
    }
  }
  __syncthreads();
  if (tid >= 216u) return;
  unsigned o = tid / 27u, f = tid - o * 27u;  // o in [0,8), f in [0,27)
  const float* wp = w2 + (((size_t)kc * 64u * 64u + (ob * 8u + o)) * 27u + f) * 2u;
  float2 acc[4];
#pragma unroll
  for (int b = 0; b < 4; b++) acc[b] = make_float2(0.f, 0.f);
#pragma unroll 8
  for (unsigned i = 0; i < 64u; i++) {
    float wr = __builtin_nontemporal_load(wp + (size_t)i * 3456u);
    float wi = __builtin_nontemporal_load(wp + (size_t)i * 3456u + 1u);
#pragma unroll
    for (int b = 0; b < 4; b++) {
      float2 a = ihl[b][i][f];
      acc[b].x += a.x * wr - a.y * wi;
      acc[b].y += a.x * wi + a.y * wr;
    }
  }
  unsigned kxl = f / 9u, kyl = (f - kxl * 9u) / 3u, kz = f % 3u;
  unsigned fg = (kxl + kxi0) * 18u + (kyl + kyi0) * 3u + kz;
#pragma unroll
  for (int b = 0; b < 4; b++)
    oh2[((size_t)(b * 64u + ob * 8u + o)) * 864u + k * 108u + fg] = acc[b];
}

// ---------------------------------------------------------------------------
// K3: fused inverse sparse DFT + synthesis. WG = (bo reversed, slab-pair).
// LDS stage-aliased: [0,16384)=hh then W; [16384,22528)=uu; [22528,24832)=gx.
__global__ __launch_bounds__(256) void k3_invsynth(const float2* __restrict__ oh2,
                                                   const float* __restrict__ x,
                                                   float* __restrict__ out) {
  __shared__ __align__(16) unsigned char smem3[24832];
  float2* hh = (float2*)smem3;              // [864]          (dead after x-inv)
  float* W = (float*)smem3;                 // [2][8][16][16] (written in z-inv)
  float2* uu = (float2*)(smem3 + 16384);    // [2][8][3][16]
  float2* gx = (float2*)(smem3 + 22528);    // [2][8][18]
  unsigned tid = threadIdx.x;
  unsigned sp = blockIdx.x & 7u;              // slab pair: nx = sp*2 + sl
  unsigned bo = 255u - (blockIdx.x >> 3);     // reversed for LLC locality
  for (unsigned i = tid; i < 864u; i += 256u)
    hh[i] = oh2[(size_t)bo * 864u + i];
  __syncthreads();
  for (unsigned i = tid; i < 288u; i += 256u) {  // x-inverse (both slabs)
    unsigned sl = i / 144u, j = i - sl * 144u;
    unsigned k = j / 18u, r = j - k * 18u;
    unsigned nx = sp * 2u + sl;
    float re = 0.f, im = 0.f;
#pragma unroll
    for (int kxi = 0; kxi < 6; kxi++) {
      float2 v = hh[k * 108u + kxi * 18 + r];
      int t16 = (KYv[kxi] * (int)nx) & 15;
      float cc = C16c[t16], sn = S16c[t16];
      re += v.x * cc - v.y * sn;
      im += v.x * sn + v.y * cc;
    }
    gx[(sl * 8u + k) * 18u + r] = make_float2(re, im);
  }
  __syncthreads();
  for (unsigned i = tid; i < 768u; i += 256u) {  // y-inverse
    unsigned sl = i / 384u, j = i - sl * 384u;
    unsigned k = j / 48u, rem = j - k * 48u;
    unsigned kz = rem >> 4, ny = rem & 15u;
    float re = 0.f, im = 0.f;
#pragma unroll
    for (int kyi = 0; kyi < 6; kyi++) {
      float2 v = gx[(sl * 8u + k) * 18u + kyi * 3 + kz];
      int t16 = (KYv[kyi] * (int)ny) & 15;
      float cc = C16c[t16], sn = S16c[t16];
      re += v.x * cc - v.y * sn;
      im += v.x * sn + v.y * cc;
    }
    uu[((sl * 8u + k) * 3u + kz) * 16u + ny] = make_float2(re, im);
  }
  __syncthreads();
  for (unsigned i = tid; i < 512u; i += 256u) {  // z-inverse + Hadamard -> W
    unsigned sl = i >> 8, ny = (i >> 4) & 15u, nz = i & 15u;
    float c1 = C16c[nz], s1 = S16c[nz];
    int t2 = (2 * nz) & 15;
    float c2 = C16c[t2], s2 = S16c[t2];
    float val[8];
#pragma unroll
    for (int k = 0; k < 8; k++) {
      float2 u0 = uu[((sl * 8u + k) * 3u + 0) * 16u + ny];
      float2 u1 = uu[((sl * 8u + k) * 3u + 1) * 16u + ny];
      float2 u2 = uu[((sl * 8u + k) * 3u + 2) * 16u + ny];
      val[k] = (u0.x + 2.f * (u1.x * c1 - u1.y * s1) + 2.f * (u2.x * c2 - u2.y * s2)) * (1.f / 4096.f);
    }
#pragma unroll
    for (int st = 1; st < 8; st <<= 1)
#pragma unroll
      for (int i2 = 0; i2 < 8; i2++)
        if (!(i2 & st)) {
          float a = val[i2], bb = val[i2 | st];
          val[i2] = a + bb;
          val[i2 | st] = a - bb;
        }
#pragma unroll
    for (int m = 0; m < 8; m++) W[((sl * 8u + m) * 16u + ny) * 16u + nz] = val[m];
  }
  __syncthreads();
  unsigned w = tid >> 6, l = tid & 63u;
  unsigned z4 = l & 15u, y2 = l >> 4;
  unsigned mmy = ((y2 >> 1) & 1u) << 1;
  const float* xp = x + ((size_t)bo << 18);
  float* op = out + ((size_t)bo << 18);
#pragma unroll
  for (unsigned sl = 0; sl < 2u; ++sl) {
#pragma unroll
    for (unsigned yg = 0; yg < 4u; ++yg) {
      unsigned Y = (yg << 4) + (w << 2) + y2;
      unsigned ny = (yg << 2) + w;
      unsigned Xa = ((sp * 2u + sl) << 2);          // xp2 = 0
      unsigned Xb = Xa + 2u;                        // xp2 = 1
      size_t offa = ((size_t)Xa << 12) + (Y << 6) + (z4 << 2);
      size_t offb = ((size_t)Xb << 12) + (Y << 6) + (z4 << 2);
      f32x4 v0a = *(const f32x4*)(xp + offa);
      f32x4 v1a = *(const f32x4*)(xp + offa + 4096u);
      f32x4 v0b = *(const f32x4*)(xp + offb);
      f32x4 v1b = *(const f32x4*)(xp + offb + 4096u);
      {
        float h0 = v0a.x + v0a.y + v1a.x + v1a.y;
        float h1 = v0a.z + v0a.w + v1a.z + v1a.w;
        float m0 = (h0 + __shfl_xor(h0, 16)) * 0.125f;
        float m1 = (h1 + __shfl_xor(h1, 16)) * 0.125f;
        unsigned mm = mmy;
        float c0 = 0.125f * W[((sl * 8u + mm) * 16u + ny) * 16u + z4] - m0;
        float c1 = 0.125f * W[((sl * 8u + (mm | 1u)) * 16u + ny) * 16u + z4] - m1;
        v0a.x += c0; v0a.y += c0; v0a.z += c1; v0a.w += c1;
        v1a.x += c0; v1a.y += c0; v1a.z += c1; v1a.w += c1;
      }
      {
        float h0 = v0b.x + v0b.y + v1b.x + v1b.y;
        float h1 = v0b.z + v0b.w + v1b.z + v1b.w;
        float m0 = (h0 + __shfl_xor(h0, 16)) * 0.125f;
        float m1 = (h1 + __shfl_xor(h1, 16)) * 0.125f;
        unsigned mm = 4u | mmy;
        float c0 = 0.125f * W[((sl * 8u + mm) * 16u + ny) * 16u + z4] - m0;
        float c1 = 0.125f * W[((sl * 8u + (mm | 1u)) * 16u + ny) * 16u + z4] - m1;
        v0b.x += c0; v0b.y += c0; v0b.z += c1; v0b.w += c1;
        v1b.x += c0; v1b.y += c0; v1b.z += c1; v1b.w += c1;
      }
      __builtin_nontemporal_store(v0a, (f32x4*)(op + offa));
      __builtin_nontemporal_store(v1a, (f32x4*)(op + offa + 4096u));
      __builtin_nontemporal_store(v0b, (f32x4*)(op + offb));
      __builtin_nontemporal_store(v1b, (f32x4*)(op + offb + 4096u));
    }
  }
}

extern "C" void kernel_launch(void* const* d_in, const int* in_sizes, int n_in,
                              void* d_out, int out_size, void* d_ws, size_t ws_size,
                              hipStream_t stream) {
  const float* x = (const float*)d_in[0];
  const float* w = (const float*)d_in[1];
  float* out = (float*)d_out;

  const size_t G_B = 4ull * 144 * 16 * 64 * 8;   // 4.72 MB
  const size_t OH_B = 256ull * 864 * 8;          // 1.77 MB

  float2 *g2, *oh2;
  char* ws = (char*)d_ws;
  if (ws_size >= G_B + OH_B) {
    g2 = (float2*)ws;
    oh2 = (float2*)(ws + G_B);
  } else {
    // oh2 must survive into K3 -> ws (1.77 MB). g2 is dead after K2; park it
    // at the tail of d_out (K3 overwrites it only after K2 completed).
    oh2 = (float2*)ws;
    g2 = (float2*)((char*)d_out + (size_t)out_size * 4 - G_B);
  }

  k1_front<<<4096, 256, 0, stream>>>(x, g2);
  k2_mix<<<256, 256, 0, stream>>>(w, g2, oh2);
  k3_invsynth<<<2048, 256, 0, stream>>>(oh2, x, out);
}